// Round 8
// baseline (65.791 us; speedup 1.0000x reference)
//
#include <hip/hip_runtime.h>

// Problem constants (match reference)
#define BATCH 16
#define IMG_H 1024
#define IMG_W 1024
#define WORDS 16                              // 1024 cols / 64 bits
#define TOTAL_PX (BATCH * IMG_H * IMG_W)      // 16777216
#define TOTAL_WORDS (TOTAL_PX / 64)           // 262144 (2 MiB as u64)
typedef unsigned long long u64;

// stable BCE-with-logits: pe = max(x,0) - x*y + log1p(exp(-|x|))
//                            = max(sgn,0) + ln2*log2(1 + 2^(-|x|*log2e)),
// where sgn = (y ? -x : x). Exact for y in {0,1}.
__device__ __forceinline__ float bce1(float x, bool y)
{
    unsigned xu = __float_as_uint(x);
    float sgn = __uint_as_float(xu ^ (y ? 0x80000000u : 0u));
    float a   = __uint_as_float(xu & 0x7fffffffu);
    float t   = __builtin_exp2f(a * -1.44269504088896340736f);
    float l2  = __builtin_log2f(1.0f + t);
    return fmaf(l2, 0.69314718055994530942f, fmaxf(sgn, 0.0f));
}

// ====== kernel A: dual-stream Σpe (unweighted) + ballot-pack targets ======
// Pure grid-free straight-line: each wave owns 512 consecutive px (8 words).
// 16 independent dword loads per thread (8 tgt + 8 lg, stride 64 floats),
// no barriers before the final reduce. 134 MB read, 2 MB write.
#define A_NT 256
#define A_WPB (A_NT / 64)                          // 4 waves/block
#define A_BLOCKS (TOTAL_WORDS / 8 / A_WPB)         // 8192

__global__ __launch_bounds__(A_NT, 8)
void wbce_main_kernel(const float* __restrict__ logits,
                      const float* __restrict__ targets,
                      u64* __restrict__ pak,
                      unsigned* __restrict__ cnt,
                      float* __restrict__ partial)
{
    __shared__ float sRed[A_WPB];
    const int tid  = threadIdx.x;
    const int lane = tid & 63;
    const int wv   = tid >> 6;
    if (blockIdx.x == 0 && tid == 0) cnt[0] = 0;   // A completes before B starts

    const int gw = blockIdx.x * A_WPB + wv;        // wave id [0, 32768)
    const size_t base = (size_t)gw * 512 + lane;
    const float* tp = targets + base;
    const float* lp = logits  + base;

    // 16 independent loads, all issued before any use
    float tv[8], lv[8];
    #pragma unroll
    for (int j = 0; j < 8; ++j) tv[j] = tp[64 * j];
    #pragma unroll
    for (int j = 0; j < 8; ++j) lv[j] = lp[64 * j];

    // pack 8 words of target bits (ballot results are wave-uniform SGPRs)
    u64 bm[8];
    #pragma unroll
    for (int j = 0; j < 8; ++j) bm[j] = __ballot(tv[j] > 0.5f);
    if (lane == 0) {
        ulonglong2* q = (ulonglong2*)(pak + (size_t)gw * 8);
        q[0] = make_ulonglong2(bm[0], bm[1]);
        q[1] = make_ulonglong2(bm[2], bm[3]);
        q[2] = make_ulonglong2(bm[4], bm[5]);
        q[3] = make_ulonglong2(bm[6], bm[7]);
    }

    // unweighted BCE over the same 8 px (y comes straight from tv)
    float acc = 0.0f;
    #pragma unroll
    for (int j = 0; j < 8; ++j) acc += bce1(lv[j], tv[j] > 0.5f);

    // wave64 shuffle tree, cross-wave via LDS, one partial per block
    #pragma unroll
    for (int off = 32; off > 0; off >>= 1)
        acc += __shfl_down(acc, off, 64);
    if (lane == 0) sRed[wv] = acc;
    __syncthreads();
    if (tid == 0) {
        float s = 0.0f;
        #pragma unroll
        for (int i = 0; i < A_WPB; ++i) s += sRed[i];
        partial[blockIdx.x] = s;
    }
}

// ====== kernel B: bitwise 9x9 morphology + boundary-word list append ======
// One thread per u64 word, L2-resident 2MB input. Words with any boundary
// bit are wave-aggregated-appended to `list`.
#define B_NT 256
__global__ __launch_bounds__(B_NT, 8)
void wbce_morph_kernel(const u64* __restrict__ pak,
                       u64* __restrict__ bndArr,
                       unsigned* __restrict__ list,
                       unsigned* __restrict__ cnt)
{
    const int idx = blockIdx.x * B_NT + threadIdx.x;   // word id [0, 262144)
    const int w   = idx & 15;
    const int row = (idx >> 4) & (IMG_H - 1);
    const int img = idx >> 14;
    const u64* ib = pak + (size_t)img * (IMG_H * WORDS);

    u64 d = 0ULL, e = ~0ULL;
    const int r0 = row >= 4 ? row - 4 : 0;             // OOB rows: neutral
    const int r1 = row <= IMG_H - 5 ? row + 4 : IMG_H - 1;
    for (int r = r0; r <= r1; ++r) {
        const u64* rp = ib + (size_t)r * WORDS;
        u64 c  = rp[w];
        u64 P  = (w > 0)  ? rp[w - 1] : 0ULL;          // OOB col: dilate fill 0
        u64 N  = (w < 15) ? rp[w + 1] : 0ULL;
        u64 Pe = (w > 0)  ? P : ~0ULL;                 // OOB col: erode fill 1
        u64 Ne = (w < 15) ? N : ~0ULL;
        u64 hd = c, he = c;
        #pragma unroll
        for (int s = 1; s <= 4; ++s) {
            hd |= (c >> s) | (N  << (64 - s));
            hd |= (c << s) | (P  >> (64 - s));
            he &= (c >> s) | (Ne << (64 - s));
            he &= (c << s) | (Pe >> (64 - s));
        }
        d |= hd;
        e &= he;
    }
    u64 bnd = d & ~e;                                  // boundary bits
    bndArr[idx] = bnd;

    // wave-aggregated append of boundary-containing word ids
    const int lane = threadIdx.x & 63;
    u64 mask = __ballot(bnd != 0ULL);
    int nb = __popcll(mask);
    unsigned base = 0;
    if (lane == 0 && nb) base = atomicAdd(cnt, (unsigned)nb);
    base = (unsigned)__shfl((int)base, 0, 64);
    if (bnd != 0ULL) {
        int off = __popcll(mask & ((1ULL << lane) - 1ULL));
        list[base + off] = (unsigned)idx;
    }
}

// ====== kernel C: sparse boundary correction: +2*pe on boundary px ======
// One WAVE per listed word: lane b handles bit b (predicated gather from
// L3-hot logits). Grid-stride over the list; per-block partials (no atomics).
#define C_NT 256
#define C_BLOCKS 2048
#define C_WAVES (C_BLOCKS * (C_NT / 64))               // 8192

__global__ __launch_bounds__(C_NT, 8)
void wbce_bnd_kernel(const float* __restrict__ logits,
                     const u64* __restrict__ pak,
                     const u64* __restrict__ bndArr,
                     const unsigned* __restrict__ list,
                     const unsigned* __restrict__ cnt,
                     float* __restrict__ partial2)
{
    __shared__ float sRed[C_NT / 64];
    const int tid = threadIdx.x, lane = tid & 63, wv = tid >> 6;
    const int gw  = blockIdx.x * (C_NT / 64) + wv;
    const unsigned n = cnt[0];

    float acc = 0.0f;
    for (unsigned e = gw; e < n; e += C_WAVES) {
        unsigned idx = list[e];                        // wave-uniform
        u64 bnd = bndArr[idx];
        u64 Cw  = pak[idx];
        bool act = (bnd >> lane) & 1ULL;
        float x = 0.0f;
        if (act) x = logits[((size_t)idx << 6) + lane];
        float pe = bce1(x, ((Cw >> lane) & 1ULL) != 0ULL);
        acc += act ? 2.0f * pe : 0.0f;                 // weight 3 = 1 (in A) + 2
    }

    #pragma unroll
    for (int off = 32; off > 0; off >>= 1)
        acc += __shfl_down(acc, off, 64);
    if (lane == 0) sRed[wv] = acc;
    __syncthreads();
    if (tid == 0) {
        float s = 0.0f;
        #pragma unroll
        for (int i = 0; i < C_NT / 64; ++i) s += sRed[i];
        partial2[blockIdx.x] = s;                      // every block writes
    }
}

// ====== kernel D: final reduce of 8192 + 2048 partials -> mean ======
#define D_NT 1024
__global__ __launch_bounds__(D_NT, 1)
void wbce_final_kernel(const float* __restrict__ partial,    // 8192 floats
                       const float* __restrict__ partial2,   // 2048 floats
                       float* __restrict__ out)
{
    __shared__ float sRed[D_NT / 64];
    const int tid = threadIdx.x;
    const float4* p4 = (const float4*)partial;         // 2048 float4
    float4 a = p4[tid];
    float4 b = p4[tid + D_NT];
    float acc = (a.x + a.y) + (a.z + a.w) + (b.x + b.y) + (b.z + b.w);
    if (tid < 512) {
        float4 c = ((const float4*)partial2)[tid];     // 512 float4
        acc += (c.x + c.y) + (c.z + c.w);
    }
    #pragma unroll
    for (int off = 32; off > 0; off >>= 1)
        acc += __shfl_down(acc, off, 64);
    if ((tid & 63) == 0) sRed[tid >> 6] = acc;
    __syncthreads();
    if (tid == 0) {
        float s = 0.0f;
        #pragma unroll
        for (int i = 0; i < D_NT / 64; ++i) s += sRed[i];
        out[0] = s * (1.0f / 16777216.0f);             // mean: 1/2^24 exact
    }
}

extern "C" void kernel_launch(void* const* d_in, const int* in_sizes, int n_in,
                              void* d_out, int out_size, void* d_ws, size_t ws_size,
                              hipStream_t stream) {
    const float* logits  = (const float*)d_in[0];
    const float* targets = (const float*)d_in[1];
    float* out = (float*)d_out;

    // scratch layout:
    //   pak   2 MiB | bnd 2 MiB | list 1 MiB | cnt 4 KiB | partial 32 KiB | partial2 8 KiB
    char* ws = (char*)d_ws;
    u64*      pak      = (u64*)ws;
    u64*      bndArr   = (u64*)(ws + (2u << 20));
    unsigned* list     = (unsigned*)(ws + (4u << 20));
    unsigned* cnt      = (unsigned*)(ws + (5u << 20));
    float*    partial  = (float*)(ws + (5u << 20) + 4096);
    float*    partial2 = (float*)(ws + (5u << 20) + 4096 + 32768);

    // A) both 67MB streams in one barrier-free pass: Σpe (unweighted) + pack
    wbce_main_kernel<<<dim3(A_BLOCKS), dim3(A_NT), 0, stream>>>(
        logits, targets, pak, cnt, partial);

    // B) word-level 9x9 bit-morphology + boundary-word list (L2 scale)
    wbce_morph_kernel<<<dim3(TOTAL_WORDS / B_NT), dim3(B_NT), 0, stream>>>(
        pak, bndArr, list, cnt);

    // C) sparse boundary correction: wave per word, lane per pixel
    wbce_bnd_kernel<<<dim3(C_BLOCKS), dim3(C_NT), 0, stream>>>(
        logits, pak, bndArr, list, cnt, partial2);

    // D) final reduce -> out[0]
    wbce_final_kernel<<<dim3(1), dim3(D_NT), 0, stream>>>(partial, partial2, out);
}

// Round 10
// 44.336 us; speedup vs baseline: 1.4839x; 1.4839x over previous
//
#include <hip/hip_runtime.h>

// Problem constants (match reference)
#define BATCH 16
#define IMG_H 1024
#define IMG_W 1024
#define WORDS 16                              // 1024 cols / 64 bits
#define TOTAL_PX (BATCH * IMG_H * IMG_W)      // 16777216
#define TOTAL_WORDS (TOTAL_PX / 64)           // 262144 (2 MiB as u64)
typedef unsigned long long u64;
typedef float f32x4 __attribute__((ext_vector_type(4)));

// stable BCE-with-logits: pe = max(x,0) - x*y + log1p(exp(-|x|))
//                            = max(sgn,0) + ln2*log2(1 + 2^(-|x|*log2e)),
// where sgn = (y ? -x : x). Exact for y in {0,1}.
__device__ __forceinline__ float bce1(float x, bool y)
{
    unsigned xu = __float_as_uint(x);
    float sgn = __uint_as_float(xu ^ (y ? 0x80000000u : 0u));
    float a   = __uint_as_float(xu & 0x7fffffffu);
    float t   = __builtin_exp2f(a * -1.44269504088896340736f);
    float l2  = __builtin_log2f(1.0f + t);
    return fmaf(l2, 0.69314718055994530942f, fmaxf(sgn, 0.0f));
}

// spread 16 bits so bit k lands at bit 4k (morton-style)
__device__ __forceinline__ u64 spread4(u64 x)
{
    x = (x | (x << 24)) & 0x000000FF000000FFull;
    x = (x | (x << 12)) & 0x000F000F000F000Full;
    x = (x | (x << 6))  & 0x0303030303030303ull;
    x = (x | (x << 3))  & 0x1111111111111111ull;
    return x;
}

// ====== kernel A: dual-stream Σpe (unweighted) + pack target bits ======
// Wave owns 512 consecutive px. Each thread: 4 asm global_load_dwordx4
// (2 tgt + 2 lg) issued back-to-back via flat 64b vaddr -> guaranteed
// 64B/thread in flight; counted s_waitcnt vmcnt(2) releases targets
// (the 2 oldest loads) while logits are still in flight.
#define A_NT 256
#define A_WPB (A_NT / 64)                          // 4 waves/block
#define A_BLOCKS (TOTAL_PX / 512 / A_WPB)          // 8192

__global__ __launch_bounds__(A_NT, 8)
void wbce_main_kernel(const float* __restrict__ logits,
                      const float* __restrict__ targets,
                      u64* __restrict__ pak,
                      float* __restrict__ partial)
{
    __shared__ float sRed[A_WPB];
    const int tid = threadIdx.x, lane = tid & 63, wv = tid >> 6;
    const int gw = blockIdx.x * A_WPB + wv;        // wave id [0, 32768)
    const size_t basePx = (size_t)gw * 512;
    const float* tpl = targets + basePx + lane * 4;   // per-lane 64b vaddr
    const float* lpl = logits  + basePx + lane * 4;

    f32x4 t0, t1, x0, x1;
    asm volatile(
        "global_load_dwordx4 %0, %4, off\n\t"
        "global_load_dwordx4 %1, %4, off offset:1024\n\t"
        "global_load_dwordx4 %2, %5, off\n\t"
        "global_load_dwordx4 %3, %5, off offset:1024"
        : "=&v"(t0), "=&v"(t1), "=&v"(x0), "=&v"(x1)
        : "v"(tpl), "v"(lpl));

    // targets (2 oldest of 4 outstanding) ready; logits still in flight
    asm volatile("s_waitcnt vmcnt(2)" : "+v"(t0), "+v"(t1));

    // ballots: bit l of bCe = (target px [base + 256*C + 4*l + e] > 0.5)
    u64 b00 = __ballot(t0.x > 0.5f), b01 = __ballot(t0.y > 0.5f);
    u64 b02 = __ballot(t0.z > 0.5f), b03 = __ballot(t0.w > 0.5f);
    u64 b10 = __ballot(t1.x > 0.5f), b11 = __ballot(t1.y > 0.5f);
    u64 b12 = __ballot(t1.z > 0.5f), b13 = __ballot(t1.w > 0.5f);

    // lane k (k<8) assembles packed word k: word bit 4j+e <- ballot e bit
    // (16*(k&3) + j), half selected by k>>2; spread4 interleaves the fields.
    {
        const int c = (lane >> 2) & 1;
        const unsigned sh = (lane & 3) * 16u;
        u64 e0 = c ? b10 : b00, e1 = c ? b11 : b01;
        u64 e2 = c ? b12 : b02, e3 = c ? b13 : b03;
        u64 word =  spread4((e0 >> sh) & 0xFFFFu)
                 | (spread4((e1 >> sh) & 0xFFFFu) << 1)
                 | (spread4((e2 >> sh) & 0xFFFFu) << 2)
                 | (spread4((e3 >> sh) & 0xFFFFu) << 3);
        if (lane < 8) pak[(size_t)gw * 8 + lane] = word;
    }

    // logits ready
    asm volatile("s_waitcnt vmcnt(0)" : "+v"(x0), "+v"(x1));

    float acc = bce1(x0.x, t0.x > 0.5f) + bce1(x0.y, t0.y > 0.5f)
              + bce1(x0.z, t0.z > 0.5f) + bce1(x0.w, t0.w > 0.5f)
              + bce1(x1.x, t1.x > 0.5f) + bce1(x1.y, t1.y > 0.5f)
              + bce1(x1.z, t1.z > 0.5f) + bce1(x1.w, t1.w > 0.5f);

    // wave64 shuffle tree, cross-wave via LDS, one partial per block
    #pragma unroll
    for (int off = 32; off > 0; off >>= 1)
        acc += __shfl_down(acc, off, 64);
    if (lane == 0) sRed[wv] = acc;
    __syncthreads();
    if (tid == 0) {
        float s = 0.0f;
        #pragma unroll
        for (int i = 0; i < A_WPB; ++i) s += sRed[i];
        partial[blockIdx.x] = s;
    }
}

// ====== kernel B: bit-morphology + wave-collective boundary correction ======
// One thread per u64 word (L2-resident 2MB pak). After computing its word's
// boundary bits, the wave iterates over nonzero-boundary lanes (ballot+ctz);
// for each, all 64 lanes gather that word's logits (L3-hot) and add 2*pe.
#define B_NT 256
__global__ __launch_bounds__(B_NT, 8)
void wbce_morph_kernel(const float* __restrict__ logits,
                       const u64* __restrict__ pak,
                       float* __restrict__ partial2)
{
    __shared__ float sRed[B_NT / 64];
    const int tid = threadIdx.x, lane = tid & 63, wv = tid >> 6;
    const int idx = blockIdx.x * B_NT + tid;       // word id [0, 262144)
    const int w   = idx & 15;
    const int row = (idx >> 4) & (IMG_H - 1);
    const int img = idx >> 14;
    const u64* ib = pak + (size_t)img * (IMG_H * WORDS);

    u64 d = 0ULL, e = ~0ULL, Cw = 0ULL;
    const int r0 = row >= 4 ? row - 4 : 0;             // OOB rows: neutral
    const int r1 = row <= IMG_H - 5 ? row + 4 : IMG_H - 1;
    for (int r = r0; r <= r1; ++r) {
        const u64* rp = ib + (size_t)r * WORDS;
        u64 c  = rp[w];
        u64 P  = (w > 0)  ? rp[w - 1] : 0ULL;          // OOB col: dilate fill 0
        u64 N  = (w < 15) ? rp[w + 1] : 0ULL;
        u64 Pe = (w > 0)  ? P : ~0ULL;                 // OOB col: erode fill 1
        u64 Ne = (w < 15) ? N : ~0ULL;
        u64 hd = c, he = c;
        #pragma unroll
        for (int s = 1; s <= 4; ++s) {
            hd |= (c >> s) | (N  << (64 - s));
            hd |= (c << s) | (P  >> (64 - s));
            he &= (c >> s) | (Ne << (64 - s));
            he &= (c << s) | (Pe >> (64 - s));
        }
        d |= hd;
        e &= he;
        if (r == row) Cw = c;
    }
    u64 bnd = d & ~e;                                  // boundary bits

    // wave-collective sparse correction: weight 3 = 1 (in A) + 2 (here)
    float acc = 0.0f;
    u64 act_mask = __ballot(bnd != 0ULL);              // wave-uniform
    const int wavebase = blockIdx.x * B_NT + wv * 64;  // word id of lane 0
    while (act_mask) {
        int s = __builtin_ctzll(act_mask);
        act_mask &= act_mask - 1;
        u64 bs = __shfl(bnd, s, 64);
        u64 cs = __shfl(Cw,  s, 64);
        if ((bs >> lane) & 1ULL) {
            float x = logits[((size_t)(wavebase + s) << 6) + lane];
            acc += 2.0f * bce1(x, ((cs >> lane) & 1ULL) != 0ULL);
        }
    }

    #pragma unroll
    for (int off = 32; off > 0; off >>= 1)
        acc += __shfl_down(acc, off, 64);
    if (lane == 0) sRed[wv] = acc;
    __syncthreads();
    if (tid == 0) {
        float s = 0.0f;
        #pragma unroll
        for (int i = 0; i < B_NT / 64; ++i) s += sRed[i];
        partial2[blockIdx.x] = s;
    }
}

// ====== kernel C: final reduce of 8192 + 1024 partials -> mean ======
#define D_NT 1024
__global__ __launch_bounds__(D_NT, 1)
void wbce_final_kernel(const float* __restrict__ partial,    // 8192 floats
                       const float* __restrict__ partial2,   // 1024 floats
                       float* __restrict__ out)
{
    __shared__ float sRed[D_NT / 64];
    const int tid = threadIdx.x;
    const float4* p4 = (const float4*)partial;         // 2048 float4
    float4 a = p4[tid];
    float4 b = p4[tid + D_NT];
    float acc = (a.x + a.y) + (a.z + a.w) + (b.x + b.y) + (b.z + b.w)
              + partial2[tid];
    #pragma unroll
    for (int off = 32; off > 0; off >>= 1)
        acc += __shfl_down(acc, off, 64);
    if ((tid & 63) == 0) sRed[tid >> 6] = acc;
    __syncthreads();
    if (tid == 0) {
        float s = 0.0f;
        #pragma unroll
        for (int i = 0; i < D_NT / 64; ++i) s += sRed[i];
        out[0] = s * (1.0f / 16777216.0f);             // mean: 1/2^24 exact
    }
}

extern "C" void kernel_launch(void* const* d_in, const int* in_sizes, int n_in,
                              void* d_out, int out_size, void* d_ws, size_t ws_size,
                              hipStream_t stream) {
    const float* logits  = (const float*)d_in[0];
    const float* targets = (const float*)d_in[1];
    float* out = (float*)d_out;

    // scratch: pak 2 MiB | partial 32 KiB | partial2 4 KiB
    char* ws = (char*)d_ws;
    u64*   pak      = (u64*)ws;
    float* partial  = (float*)(ws + (2u << 20));
    float* partial2 = (float*)(ws + (2u << 20) + 32768);

    // A) both 67MB streams, asm-forced MLP: Σpe (unweighted) + packed bits
    wbce_main_kernel<<<dim3(A_BLOCKS), dim3(A_NT), 0, stream>>>(
        logits, targets, pak, partial);

    // B) word-level 9x9 bit-morphology + sparse boundary correction
    wbce_morph_kernel<<<dim3(TOTAL_WORDS / B_NT), dim3(B_NT), 0, stream>>>(
        logits, pak, partial2);

    // C) final reduce -> out[0] (plain store; no zeroing needed anywhere)
    wbce_final_kernel<<<dim3(1), dim3(D_NT), 0, stream>>>(partial, partial2, out);
}